// Round 3
// baseline (110.209 us; speedup 1.0000x reference)
//
#include <hip/hip_runtime.h>
#include <hip/hip_bf16.h>

typedef __attribute__((ext_vector_type(8))) short bf16x8;
typedef __attribute__((ext_vector_type(4))) short short4v;
typedef __attribute__((ext_vector_type(4))) float f32x4;

#define B_SZ 8
#define T_SZ 2048
#define C_SZ 768
#define H_SZ 64
#define WPB 4   // kv-split width per q-tile

__device__ __forceinline__ short f2bs(float f){
  __hip_bfloat16 h = __float2bfloat16(f);
  short s; __builtin_memcpy(&s, &h, 2); return s;
}

// --- K0: coalesced transpose W[768][64] -> Wt[192][768] bf16 (q|k|v) ---
__global__ __launch_bounds__(256) void prep_wt(const float* __restrict__ Wq, const float* __restrict__ Wk,
                        const float* __restrict__ Wv, short* __restrict__ Wt){
  __shared__ float tile[64][65];
  int mat = blockIdx.x / 12, kblk = blockIdx.x % 12;
  const float* W = (mat == 0) ? Wq : (mat == 1 ? Wk : Wv);
  int k0 = kblk * 64;
  int tid = threadIdx.x;
  int r = tid >> 2, cq = (tid & 3) * 16;
  #pragma unroll
  for (int i = 0; i < 4; ++i){
    float4 v = *reinterpret_cast<const float4*>(&W[(k0 + r)*H_SZ + cq + i*4]);
    tile[r][cq + i*4 + 0] = v.x;
    tile[r][cq + i*4 + 1] = v.y;
    tile[r][cq + i*4 + 2] = v.z;
    tile[r][cq + i*4 + 3] = v.w;
  }
  __syncthreads();
  int n = tid >> 2, kq = (tid & 3) * 16;
  bf16x8 o0, o1;
  #pragma unroll
  for (int e = 0; e < 8; ++e){
    o0[e] = f2bs(tile[kq + e][n]);
    o1[e] = f2bs(tile[kq + 8 + e][n]);
  }
  *reinterpret_cast<bf16x8*>(&Wt[(mat*64 + n)*C_SZ + k0 + kq])     = o0;
  *reinterpret_cast<bf16x8*>(&Wt[(mat*64 + n)*C_SZ + k0 + kq + 8]) = o1;
}

// --- K1: barrier-free QKV GEMM. BM=32, 8 waves (2M x 4N), A-frags direct from global ---
__global__ __launch_bounds__(512) void qkv_gemm(const float* __restrict__ x, const short* __restrict__ Wt,
                         short* __restrict__ qb, short* __restrict__ kb, short* __restrict__ vT){
  int tid = threadIdx.x;
  int wv = tid >> 6, lane = tid & 63, lhi = lane >> 4, llo = lane & 15;
  int wm = wv >> 2, wn = wv & 3;
  long m0 = (long)blockIdx.x * 32;
  const float* xrow = &x[(m0 + wm*16 + llo)*C_SZ + lhi*8];

  f32x4 acc[3];
  #pragma unroll
  for (int j = 0; j < 3; ++j) acc[j] = (f32x4){0.f,0.f,0.f,0.f};

  float4 xa0 = *reinterpret_cast<const float4*>(xrow);
  float4 xa1 = *reinterpret_cast<const float4*>(xrow + 4);
  float4 xb0 = *reinterpret_cast<const float4*>(xrow + 32);
  float4 xb1 = *reinterpret_cast<const float4*>(xrow + 36);

  for (int k0 = 0; k0 < C_SZ; k0 += 64){
    float4 c00 = xa0, c01 = xa1, c10 = xb0, c11 = xb1;
    if (k0 + 64 < C_SZ){                    // prefetch stays in flight: no barrier to drain it
      xa0 = *reinterpret_cast<const float4*>(xrow + k0 + 64);
      xa1 = *reinterpret_cast<const float4*>(xrow + k0 + 68);
      xb0 = *reinterpret_cast<const float4*>(xrow + k0 + 96);
      xb1 = *reinterpret_cast<const float4*>(xrow + k0 + 100);
    }
    bf16x8 af0, af1;
    af0[0]=f2bs(c00.x); af0[1]=f2bs(c00.y); af0[2]=f2bs(c00.z); af0[3]=f2bs(c00.w);
    af0[4]=f2bs(c01.x); af0[5]=f2bs(c01.y); af0[6]=f2bs(c01.z); af0[7]=f2bs(c01.w);
    af1[0]=f2bs(c10.x); af1[1]=f2bs(c10.y); af1[2]=f2bs(c10.z); af1[3]=f2bs(c10.w);
    af1[4]=f2bs(c11.x); af1[5]=f2bs(c11.y); af1[6]=f2bs(c11.z); af1[7]=f2bs(c11.w);
    #pragma unroll
    for (int j = 0; j < 3; ++j){
      int n = wn*48 + j*16 + llo;
      bf16x8 b0 = *reinterpret_cast<const bf16x8*>(&Wt[n*C_SZ + k0 + lhi*8]);
      acc[j] = __builtin_amdgcn_mfma_f32_16x16x32_bf16(af0, b0, acc[j], 0, 0, 0);
    }
    #pragma unroll
    for (int j = 0; j < 3; ++j){
      int n = wn*48 + j*16 + llo;
      bf16x8 b1 = *reinterpret_cast<const bf16x8*>(&Wt[n*C_SZ + k0 + 32 + lhi*8]);
      acc[j] = __builtin_amdgcn_mfma_f32_16x16x32_bf16(af1, b1, acc[j], 0, 0, 0);
    }
  }

  long mbase = m0 + wm*16 + lhi*4;
  #pragma unroll
  for (int j = 0; j < 3; ++j){
    int n = wn*48 + j*16 + llo;
    int mat = n >> 6, c = n & 63;
    if (mat == 2){
      long b = mbase >> 11, t = mbase & 2047;
      short4v p;
      #pragma unroll
      for (int reg = 0; reg < 4; ++reg) p[reg] = f2bs(acc[j][reg]);
      *reinterpret_cast<short4v*>(&vT[(b*H_SZ + c)*T_SZ + t]) = p;
    } else {
      short* dst = (mat == 0) ? qb : kb;
      #pragma unroll
      for (int reg = 0; reg < 4; ++reg)
        dst[(mbase + reg)*H_SZ + c] = f2bs(acc[j][reg]);
    }
  }
}

// --- K2: flash attention, swapped QK^T (in-lane softmax), 4-way kv split, paired q-tiles ---
__global__ __launch_bounds__(512) void attn_fwd(const short* __restrict__ qb, const short* __restrict__ kb,
                        const short* __restrict__ vT, const float* __restrict__ bias_table,
                        float* __restrict__ out){
  __shared__ float o_part[8][16][65];       // [wave][q][d], +1 pad
  __shared__ float m_part[8][16];
  __shared__ float l_part[8][16];
  __shared__ short P_lds[8][16][72];        // [wave][q][kv], +8 pad

  int tid = threadIdx.x;
  int wv = tid >> 6, lane = tid & 63, lhi = lane >> 4, llo = lane & 15;
  int g = wv >> 2, ws = wv & 3;
  int b = blockIdx.x >> 6, jj = blockIdx.x & 63;
  int qt = g ? (127 - jj) : jj;             // two 4-wave groups, paired tiles: block work constant
  int q0 = qt * 16;
  int q = q0 + llo;

  const short* qrow = &qb[((long)(b*T_SZ + q))*H_SZ + lhi*8];
  bf16x8 qf0 = *reinterpret_cast<const bf16x8*>(qrow);
  bf16x8 qf1 = *reinterpret_cast<const bf16x8*>(qrow + 32);
  const short* kbase = kb + (long)b*T_SZ*H_SZ;
  const short* vbase = vT + (long)b*H_SZ*T_SZ;

  float m_r = -1e30f, l_r = 0.f;
  f32x4 o[4];
  #pragma unroll
  for (int df = 0; df < 4; ++df) o[df] = (f32x4){0.f,0.f,0.f,0.f};

  int nkt = (qt >> 2) + 1;
  for (int kt = ws; kt < nkt; kt += WPB){
    int kv0 = kt * 64;
    f32x4 s[4];
    #pragma unroll
    for (int f = 0; f < 4; ++f){            // S^T = K·Q^T: lane holds S[kv][q=llo]
      const short* kr = kbase + (long)(kv0 + f*16 + llo)*H_SZ + lhi*8;
      bf16x8 kf0 = *reinterpret_cast<const bf16x8*>(kr);
      bf16x8 kf1 = *reinterpret_cast<const bf16x8*>(kr + 32);
      f32x4 t = (f32x4){0.f,0.f,0.f,0.f};
      t = __builtin_amdgcn_mfma_f32_16x16x32_bf16(kf0, qf0, t, 0, 0, 0);
      t = __builtin_amdgcn_mfma_f32_16x16x32_bf16(kf1, qf1, t, 0, 0, 0);
      s[f] = t;
    }
    float rm = -1e30f;
    #pragma unroll
    for (int f = 0; f < 4; ++f)
      #pragma unroll
      for (int r = 0; r < 4; ++r){
        int kv = kv0 + f*16 + lhi*4 + r;
        int rel = q - kv;
        float bv = bias_table[rel > 0 ? rel : 0];
        float sv = (rel >= 0) ? fmaf(s[f][r], 0.125f, bv) : -1e30f;
        s[f][r] = sv;
        rm = fmaxf(rm, sv);
      }
    rm = fmaxf(rm, __shfl_xor(rm, 16));     // only 2 cross-lane ops (lhi groups)
    rm = fmaxf(rm, __shfl_xor(rm, 32));
    float mnew = fmaxf(m_r, rm);
    float corr = __expf(m_r - mnew);
    m_r = mnew;
    float rs = 0.f;
    #pragma unroll
    for (int f = 0; f < 4; ++f)
      #pragma unroll
      for (int r = 0; r < 4; ++r){
        float p = __expf(s[f][r] - mnew);
        s[f][r] = p;
        rs += p;
      }
    rs += __shfl_xor(rs, 16);
    rs += __shfl_xor(rs, 32);
    l_r = l_r * corr + rs;
    #pragma unroll
    for (int df = 0; df < 4; ++df) o[df] = o[df] * corr;
    // P^T -> LDS [q][kv]: 4x 8B writes, then read B-frags
    #pragma unroll
    for (int f = 0; f < 4; ++f){
      short4v pk;
      #pragma unroll
      for (int r = 0; r < 4; ++r) pk[r] = f2bs(s[f][r]);
      *reinterpret_cast<short4v*>(&P_lds[wv][llo][f*16 + lhi*4]) = pk;
    }
    bf16x8 pb0 = *reinterpret_cast<const bf16x8*>(&P_lds[wv][llo][lhi*8]);
    bf16x8 pb1 = *reinterpret_cast<const bf16x8*>(&P_lds[wv][llo][32 + lhi*8]);
    #pragma unroll
    for (int df = 0; df < 4; ++df){         // O^T = V^T·P^T: lane holds O[d][q=llo]
      const short* vr = vbase + (long)(df*16 + llo)*T_SZ + kv0 + lhi*8;
      bf16x8 vf0 = *reinterpret_cast<const bf16x8*>(vr);
      bf16x8 vf1 = *reinterpret_cast<const bf16x8*>(vr + 32);
      o[df] = __builtin_amdgcn_mfma_f32_16x16x32_bf16(vf0, pb0, o[df], 0, 0, 0);
      o[df] = __builtin_amdgcn_mfma_f32_16x16x32_bf16(vf1, pb1, o[df], 0, 0, 0);
    }
  }

  // write flash partials
  #pragma unroll
  for (int df = 0; df < 4; ++df)
    #pragma unroll
    for (int r = 0; r < 4; ++r)
      o_part[wv][llo][df*16 + lhi*4 + r] = o[df][r];
  if (lhi == 0){ m_part[wv][llo] = m_r; l_part[wv][llo] = l_r; }
  __syncthreads();

  // merge 4 partials per group; 512 threads cover both groups' 16x64 outputs
  int g2 = tid >> 8, r2 = tid & 255;
  int d = r2 & 63, q4 = r2 >> 6;
  int qt2 = g2 ? (127 - jj) : jj;
  long obase = ((long)(b*T_SZ + qt2*16))*H_SZ;
  #pragma unroll
  for (int i = 0; i < 4; ++i){
    int qq = q4*4 + i;
    float mstar = m_part[g2*4][qq];
    #pragma unroll
    for (int w = 1; w < 4; ++w) mstar = fmaxf(mstar, m_part[g2*4 + w][qq]);
    float lsum = 0.f, osum = 0.f;
    #pragma unroll
    for (int w = 0; w < 4; ++w){
      float sc = __expf(m_part[g2*4 + w][qq] - mstar);
      lsum += l_part[g2*4 + w][qq] * sc;
      osum += o_part[g2*4 + w][qq][d] * sc;
    }
    out[obase + (long)qq*H_SZ + d] = osum / lsum;
  }
}

extern "C" void kernel_launch(void* const* d_in, const int* in_sizes, int n_in,
                              void* d_out, int out_size, void* d_ws, size_t ws_size,
                              hipStream_t stream){
  const float* x    = (const float*)d_in[0];
  const float* Wq   = (const float*)d_in[1];
  const float* Wk   = (const float*)d_in[2];
  const float* Wv   = (const float*)d_in[3];
  const float* bias = (const float*)d_in[4];
  float* out = (float*)d_out;

  const size_t NTOK = (size_t)B_SZ * T_SZ * H_SZ;   // 1,048,576
  short* qb = (short*)d_ws;
  short* kb = qb + NTOK;
  short* vT = kb + NTOK;
  short* Wt = vT + NTOK;                            // 192*768 shorts

  prep_wt<<<36, 256, 0, stream>>>(Wq, Wk, Wv, Wt);
  qkv_gemm<<<512, 512, 0, stream>>>(x, Wt, qb, kb, vT);
  attn_fwd<<<512, 512, 0, stream>>>(qb, kb, vT, bias, out);
}

// Round 4
// 106.096 us; speedup vs baseline: 1.0388x; 1.0388x over previous
//
#include <hip/hip_runtime.h>
#include <hip/hip_bf16.h>

typedef __attribute__((ext_vector_type(8))) short bf16x8;
typedef __attribute__((ext_vector_type(4))) short short4v;
typedef __attribute__((ext_vector_type(4))) float f32x4;

#define B_SZ 8
#define T_SZ 2048
#define C_SZ 768
#define H_SZ 64

__device__ __forceinline__ short f2bs(float f){
  __hip_bfloat16 h = __float2bfloat16(f);
  short s; __builtin_memcpy(&s, &h, 2); return s;
}
__device__ __forceinline__ f32x4 vmax4(f32x4 a, f32x4 b){
  f32x4 r; r[0]=fmaxf(a[0],b[0]); r[1]=fmaxf(a[1],b[1]);
  r[2]=fmaxf(a[2],b[2]); r[3]=fmaxf(a[3],b[3]); return r;
}

// --- K0: Wt transpose (blocks 0-35) + log2-scaled bias table (blocks 36-43) ---
__global__ __launch_bounds__(256) void prep_wt(const float* __restrict__ Wq, const float* __restrict__ Wk,
                        const float* __restrict__ Wv, const float* __restrict__ bias,
                        short* __restrict__ Wt, float* __restrict__ bsc){
  int tid = threadIdx.x;
  if (blockIdx.x >= 36){
    int i = (blockIdx.x - 36)*256 + tid;
    bsc[i] = bias[i] * 1.44269504f;         // log2e — softmax runs in exp2 domain
    return;
  }
  __shared__ float tile[64][65];
  int mat = blockIdx.x / 12, kblk = blockIdx.x % 12;
  const float* W = (mat == 0) ? Wq : (mat == 1 ? Wk : Wv);
  int k0 = kblk * 64;
  int r = tid >> 2, cq = (tid & 3) * 16;
  #pragma unroll
  for (int i = 0; i < 4; ++i){
    float4 v = *reinterpret_cast<const float4*>(&W[(k0 + r)*H_SZ + cq + i*4]);
    tile[r][cq + i*4 + 0] = v.x; tile[r][cq + i*4 + 1] = v.y;
    tile[r][cq + i*4 + 2] = v.z; tile[r][cq + i*4 + 3] = v.w;
  }
  __syncthreads();
  int n = tid >> 2, kq = (tid & 3) * 16;
  bf16x8 o0, o1;
  #pragma unroll
  for (int e = 0; e < 8; ++e){
    o0[e] = f2bs(tile[kq + e][n]);
    o1[e] = f2bs(tile[kq + 8 + e][n]);
  }
  *reinterpret_cast<bf16x8*>(&Wt[(mat*64 + n)*C_SZ + k0 + kq])     = o0;
  *reinterpret_cast<bf16x8*>(&Wt[(mat*64 + n)*C_SZ + k0 + kq + 8]) = o1;
}

// --- K1: QKV GEMM, per-wave LDS staging (coalesced, barrier-free), N-split 2 ---
__global__ __launch_bounds__(256) void qkv_gemm(const float* __restrict__ x, const short* __restrict__ Wt,
                         short* __restrict__ qb, short* __restrict__ kb, short* __restrict__ vT){
  __shared__ short As[4][2][1024];          // [wave][dbuf][16 rows x 64 k], granule-swizzled
  int tid = threadIdx.x;
  int wv = tid >> 6, lane = tid & 63, lhi = lane >> 4, llo = lane & 15;
  int wm = wv >> 1, wn = wv & 1;
  long R0 = (long)blockIdx.x * 32 + wm * 16;
  int r = lane >> 2, c4 = lane & 3;         // staging: 16 rows x 4 lanes, 64B segments
  const float* xs = &x[(R0 + r)*C_SZ + c4*16];
  short* myA = &As[wv][0][0];
  int r7 = r & 7;
  // swizzled write offsets (shorts): granule g = c4*2 (+1), g' = g ^ (r&7)
  int wo0 = r*64 + ((c4*2    ) ^ r7)*8;     // u=0,1 target granule
  int wo1 = r*64 + ((c4*2 + 1) ^ r7)*8;     // u=2,3 target granule
  int llo7 = llo & 7;
  int ro0 = llo*64 + (( lhi     ) ^ llo7)*8;
  int ro1 = llo*64 + ((4 + lhi  ) ^ llo7)*8;

  f32x4 acc[6];
  #pragma unroll
  for (int j = 0; j < 6; ++j) acc[j] = (f32x4){0.f,0.f,0.f,0.f};

  float4 n0, n1, n2, n3;
#define LOADX(T) { const float* p = xs + (T)*64; \
    n0 = *reinterpret_cast<const float4*>(p); \
    n1 = *reinterpret_cast<const float4*>(p + 4); \
    n2 = *reinterpret_cast<const float4*>(p + 8); \
    n3 = *reinterpret_cast<const float4*>(p + 12); }
#define STAGE_WRITE(BUF) { int bb = (BUF)*1024; short4v w; \
    w[0]=f2bs(n0.x); w[1]=f2bs(n0.y); w[2]=f2bs(n0.z); w[3]=f2bs(n0.w); \
    *reinterpret_cast<short4v*>(&myA[bb + wo0])     = w; \
    w[0]=f2bs(n1.x); w[1]=f2bs(n1.y); w[2]=f2bs(n1.z); w[3]=f2bs(n1.w); \
    *reinterpret_cast<short4v*>(&myA[bb + wo0 + 4]) = w; \
    w[0]=f2bs(n2.x); w[1]=f2bs(n2.y); w[2]=f2bs(n2.z); w[3]=f2bs(n2.w); \
    *reinterpret_cast<short4v*>(&myA[bb + wo1])     = w; \
    w[0]=f2bs(n3.x); w[1]=f2bs(n3.y); w[2]=f2bs(n3.z); w[3]=f2bs(n3.w); \
    *reinterpret_cast<short4v*>(&myA[bb + wo1 + 4]) = w; }

  LOADX(0); STAGE_WRITE(0); LOADX(1);

  for (int t = 0; t < 12; ++t){
    int cb = t & 1;
    bf16x8 af0 = *reinterpret_cast<const bf16x8*>(&myA[cb*1024 + ro0]);
    bf16x8 af1 = *reinterpret_cast<const bf16x8*>(&myA[cb*1024 + ro1]);
    if (t < 11) STAGE_WRITE(cb ^ 1);        // tile t+1 (regs arrived during prev MFMAs)
    if (t < 10) LOADX(t + 2);               // depth-2 prefetch flies over MFMA phase
    int k0 = t * 64;
    #pragma unroll
    for (int j = 0; j < 6; ++j){
      const short* bp = &Wt[(wn*96 + j*16 + llo)*C_SZ + k0 + lhi*8];
      bf16x8 b0 = *reinterpret_cast<const bf16x8*>(bp);
      bf16x8 b1 = *reinterpret_cast<const bf16x8*>(bp + 32);
      acc[j] = __builtin_amdgcn_mfma_f32_16x16x32_bf16(af0, b0, acc[j], 0, 0, 0);
      acc[j] = __builtin_amdgcn_mfma_f32_16x16x32_bf16(af1, b1, acc[j], 0, 0, 0);
    }
  }
#undef LOADX
#undef STAGE_WRITE

  long mbase = R0 + lhi*4;
  #pragma unroll
  for (int j = 0; j < 6; ++j){
    int n = wn*96 + j*16 + llo;
    int mat = n >> 6, c = n & 63;
    if (mat == 2){
      long b = mbase >> 11, t = mbase & 2047;
      short4v p;
      #pragma unroll
      for (int reg = 0; reg < 4; ++reg) p[reg] = f2bs(acc[j][reg]);
      *reinterpret_cast<short4v*>(&vT[(b*H_SZ + c)*T_SZ + t]) = p;
    } else {
      short* dst = (mat == 0) ? qb : kb;
      #pragma unroll
      for (int reg = 0; reg < 4; ++reg)
        dst[(mbase + reg)*H_SZ + c] = f2bs(acc[j][reg]);
    }
  }
}

// --- K2: flash attention, swapped QK^T, K/V register pipeline, log2 softmax, defer-max ---
__global__ __launch_bounds__(512, 4) void attn_fwd(const short* __restrict__ qb, const short* __restrict__ kb,
                        const short* __restrict__ vT, const float* __restrict__ bsc,
                        float* __restrict__ out){
  __shared__ float o_part[8][16][65];
  __shared__ float m_part[8][16];
  __shared__ float l_part[8][16];
  __shared__ short P_lds[8][16][72];

  int tid = threadIdx.x;
  int wv = tid >> 6, lane = tid & 63, lhi = lane >> 4, llo = lane & 15;
  int g = wv >> 2, ws = wv & 3;
  int b = blockIdx.x >> 6, jj = blockIdx.x & 63;
  int qt = g ? (127 - jj) : jj;
  int q0 = qt * 16;
  int q = q0 + llo;

  const short* qrow = &qb[((long)(b*T_SZ + q))*H_SZ + lhi*8];
  bf16x8 qf0 = *reinterpret_cast<const bf16x8*>(qrow);
  bf16x8 qf1 = *reinterpret_cast<const bf16x8*>(qrow + 32);
  const short* kbase = kb + (long)b*T_SZ*H_SZ;
  const short* vbase = vT + (long)b*H_SZ*T_SZ;

  float m_r = -1e30f, l_r = 0.f;
  f32x4 o[4];
  #pragma unroll
  for (int df = 0; df < 4; ++df) o[df] = (f32x4){0.f,0.f,0.f,0.f};

  bf16x8 kf[4][2], vf[4][2];
#define LOADK(KT) { long kv0_ = (long)(KT)*64; \
    _Pragma("unroll") for (int f_ = 0; f_ < 4; ++f_){ \
      const short* kr_ = kbase + (kv0_ + f_*16 + llo)*H_SZ + lhi*8; \
      kf[f_][0] = *reinterpret_cast<const bf16x8*>(kr_); \
      kf[f_][1] = *reinterpret_cast<const bf16x8*>(kr_ + 32); } }
#define LOADV(KT) { long kv0_ = (long)(KT)*64; \
    _Pragma("unroll") for (int d_ = 0; d_ < 4; ++d_){ \
      const short* vr_ = vbase + (long)(d_*16 + llo)*T_SZ + kv0_ + lhi*8; \
      vf[d_][0] = *reinterpret_cast<const bf16x8*>(vr_); \
      vf[d_][1] = *reinterpret_cast<const bf16x8*>(vr_ + 32); } }

  int nkt = (qt >> 2) + 1;
  int kt = ws;
  if (kt < nkt){ LOADK(kt); LOADV(kt); }
  while (kt < nkt){
    int kv0 = kt * 64;
    f32x4 s[4];
    #pragma unroll
    for (int f = 0; f < 4; ++f){
      f32x4 t = (f32x4){0.f,0.f,0.f,0.f};
      t = __builtin_amdgcn_mfma_f32_16x16x32_bf16(kf[f][0], qf0, t, 0, 0, 0);
      t = __builtin_amdgcn_mfma_f32_16x16x32_bf16(kf[f][1], qf1, t, 0, 0, 0);
      s[f] = t;
    }
    int ktn = kt + 4;
    bool more = ktn < nkt;
    if (more) LOADK(ktn);                   // flies across softmax + PV
    // bias + causal mask, log2 domain (0.125 * log2e = 0.18033688)
    #pragma unroll
    for (int f = 0; f < 4; ++f)
      #pragma unroll
      for (int rg = 0; rg < 4; ++rg){
        int kv = kv0 + f*16 + lhi*4 + rg;
        int rel = q - kv;
        float bv = bsc[rel > 0 ? rel : 0];
        s[f][rg] = (rel >= 0) ? fmaf(s[f][rg], 0.18033688f, bv) : -1e30f;
      }
    f32x4 tm = vmax4(vmax4(s[0], s[1]), vmax4(s[2], s[3]));
    float pmax = fmaxf(fmaxf(tm[0], tm[1]), fmaxf(tm[2], tm[3]));
    pmax = fmaxf(pmax, __shfl_xor(pmax, 16));
    pmax = fmaxf(pmax, __shfl_xor(pmax, 32));
    bool keep = __all(pmax <= m_r + 8.0f);  // defer-max: P bounded by 2^8
    if (!keep){
      float mnew = fmaxf(m_r, pmax);
      float corr = exp2f(m_r - mnew);
      m_r = mnew;
      l_r *= corr;
      #pragma unroll
      for (int df = 0; df < 4; ++df) o[df] = o[df] * corr;
    }
    #pragma unroll
    for (int f = 0; f < 4; ++f)
      #pragma unroll
      for (int rg = 0; rg < 4; ++rg)
        s[f][rg] = exp2f(s[f][rg] - m_r);
    f32x4 va = (s[0] + s[1]) + (s[2] + s[3]);
    float rs = (va[0] + va[1]) + (va[2] + va[3]);
    rs += __shfl_xor(rs, 16);
    rs += __shfl_xor(rs, 32);
    l_r += rs;
    // P^T -> LDS [q][kv] -> B-frags
    #pragma unroll
    for (int f = 0; f < 4; ++f){
      short4v pk;
      #pragma unroll
      for (int rg = 0; rg < 4; ++rg) pk[rg] = f2bs(s[f][rg]);
      *reinterpret_cast<short4v*>(&P_lds[wv][llo][f*16 + lhi*4]) = pk;
    }
    bf16x8 pb0 = *reinterpret_cast<const bf16x8*>(&P_lds[wv][llo][lhi*8]);
    bf16x8 pb1 = *reinterpret_cast<const bf16x8*>(&P_lds[wv][llo][32 + lhi*8]);
    #pragma unroll
    for (int df = 0; df < 4; ++df){
      o[df] = __builtin_amdgcn_mfma_f32_16x16x32_bf16(vf[df][0], pb0, o[df], 0, 0, 0);
      o[df] = __builtin_amdgcn_mfma_f32_16x16x32_bf16(vf[df][1], pb1, o[df], 0, 0, 0);
    }
    if (more) LOADV(ktn);                   // flies across next QK + softmax
    kt = ktn;
  }
#undef LOADK
#undef LOADV

  #pragma unroll
  for (int df = 0; df < 4; ++df)
    #pragma unroll
    for (int rg = 0; rg < 4; ++rg)
      o_part[wv][llo][df*16 + lhi*4 + rg] = o[df][rg];
  if (lhi == 0){ m_part[wv][llo] = m_r; l_part[wv][llo] = l_r; }
  __syncthreads();

  int g2 = tid >> 8, r2 = tid & 255;
  int d = r2 & 63, q4 = r2 >> 6;
  int qt2 = g2 ? (127 - jj) : jj;
  long obase = ((long)(b*T_SZ + qt2*16))*H_SZ;
  #pragma unroll
  for (int i = 0; i < 4; ++i){
    int qq = q4*4 + i;
    float mstar = m_part[g2*4][qq];
    #pragma unroll
    for (int w = 1; w < 4; ++w) mstar = fmaxf(mstar, m_part[g2*4 + w][qq]);
    float lsum = 0.f, osum = 0.f;
    #pragma unroll
    for (int w = 0; w < 4; ++w){
      float sc = exp2f(m_part[g2*4 + w][qq] - mstar);
      lsum += l_part[g2*4 + w][qq] * sc;
      osum += o_part[g2*4 + w][qq][d] * sc;
    }
    out[obase + (long)qq*H_SZ + d] = osum / lsum;
  }
}

extern "C" void kernel_launch(void* const* d_in, const int* in_sizes, int n_in,
                              void* d_out, int out_size, void* d_ws, size_t ws_size,
                              hipStream_t stream){
  const float* x    = (const float*)d_in[0];
  const float* Wq   = (const float*)d_in[1];
  const float* Wk   = (const float*)d_in[2];
  const float* Wv   = (const float*)d_in[3];
  const float* bias = (const float*)d_in[4];
  float* out = (float*)d_out;

  const size_t NTOK = (size_t)B_SZ * T_SZ * H_SZ;   // 1,048,576
  short* qb = (short*)d_ws;
  short* kb = qb + NTOK;
  short* vT = kb + NTOK;
  short* Wt = vT + NTOK;                            // 192*768 shorts
  float* bsc = (float*)(Wt + 192*C_SZ);             // 2048 floats, 4B-aligned

  prep_wt<<<44, 256, 0, stream>>>(Wq, Wk, Wv, bias, Wt, bsc);
  qkv_gemm<<<512, 256, 0, stream>>>(x, Wt, qb, kb, vT);
  attn_fwd<<<512, 512, 0, stream>>>(qb, kb, vT, bsc, out);
}

// Round 5
// 92.007 us; speedup vs baseline: 1.1978x; 1.1531x over previous
//
#include <hip/hip_runtime.h>
#include <hip/hip_bf16.h>

typedef __attribute__((ext_vector_type(8))) short bf16x8;
typedef __attribute__((ext_vector_type(4))) short short4v;
typedef __attribute__((ext_vector_type(4))) float f32x4;

#define B_SZ 8
#define T_SZ 2048
#define C_SZ 768
#define H_SZ 64

__device__ __forceinline__ short f2bs(float f){
  __hip_bfloat16 h = __float2bfloat16(f);
  short s; __builtin_memcpy(&s, &h, 2); return s;
}
__device__ __forceinline__ f32x4 vmax4(f32x4 a, f32x4 b){
  f32x4 r; r[0]=fmaxf(a[0],b[0]); r[1]=fmaxf(a[1],b[1]);
  r[2]=fmaxf(a[2],b[2]); r[3]=fmaxf(a[3],b[3]); return r;
}

// --- K0: Wt transpose (blocks 0-35) + log2-scaled bias table (blocks 36-43) ---
__global__ __launch_bounds__(256) void prep_wt(const float* __restrict__ Wq, const float* __restrict__ Wk,
                        const float* __restrict__ Wv, const float* __restrict__ bias,
                        short* __restrict__ Wt, float* __restrict__ bsc){
  int tid = threadIdx.x;
  if (blockIdx.x >= 36){
    int i = (blockIdx.x - 36)*256 + tid;
    bsc[i] = bias[i] * 1.44269504f;         // log2e — softmax in exp2 domain
    return;
  }
  __shared__ float tile[64][65];
  int mat = blockIdx.x / 12, kblk = blockIdx.x % 12;
  const float* W = (mat == 0) ? Wq : (mat == 1 ? Wk : Wv);
  int k0 = kblk * 64;
  int r = tid >> 2, cq = (tid & 3) * 16;
  #pragma unroll
  for (int i = 0; i < 4; ++i){
    float4 v = *reinterpret_cast<const float4*>(&W[(k0 + r)*H_SZ + cq + i*4]);
    tile[r][cq + i*4 + 0] = v.x; tile[r][cq + i*4 + 1] = v.y;
    tile[r][cq + i*4 + 2] = v.z; tile[r][cq + i*4 + 3] = v.w;
  }
  __syncthreads();
  int n = tid >> 2, kq = (tid & 3) * 16;
  bf16x8 o0, o1;
  #pragma unroll
  for (int e = 0; e < 8; ++e){
    o0[e] = f2bs(tile[kq + e][n]);
    o1[e] = f2bs(tile[kq + 8 + e][n]);
  }
  *reinterpret_cast<bf16x8*>(&Wt[(mat*64 + n)*C_SZ + k0 + kq])     = o0;
  *reinterpret_cast<bf16x8*>(&Wt[(mat*64 + n)*C_SZ + k0 + kq + 8]) = o1;
}

// --- K1: QKV GEMM. BM=16, 1024 blocks x 4 waves (col-split), per-wave LDS staging,
//     explicit double-buffered B regs for load ILP ---
__global__ __launch_bounds__(256, 4) void qkv_gemm(const float* __restrict__ x, const short* __restrict__ Wt,
                         short* __restrict__ qb, short* __restrict__ kb, short* __restrict__ vT){
  __shared__ short As[4][2][1024];          // [wave][dbuf][16 rows x 64 k], granule-swizzled
  int tid = threadIdx.x;
  int wv = tid >> 6, lane = tid & 63, lhi = lane >> 4, llo = lane & 15;
  long R0 = (long)blockIdx.x * 16;
  int r = lane >> 2, c4 = lane & 3;
  const float* xs = &x[(R0 + r)*C_SZ + c4*16];
  short* myA = &As[wv][0][0];
  int r7 = r & 7;
  int wo0 = r*64 + ((c4*2    ) ^ r7)*8;
  int wo1 = r*64 + ((c4*2 + 1) ^ r7)*8;
  int llo7 = llo & 7;
  int ro0 = llo*64 + (( lhi    ) ^ llo7)*8;
  int ro1 = llo*64 + ((4 + lhi) ^ llo7)*8;

  f32x4 acc[3];
  #pragma unroll
  for (int j = 0; j < 3; ++j) acc[j] = (f32x4){0.f,0.f,0.f,0.f};

  const short* bp0 = &Wt[(wv*48 +  0 + llo)*C_SZ + lhi*8];
  const short* bp1 = &Wt[(wv*48 + 16 + llo)*C_SZ + lhi*8];
  const short* bp2 = &Wt[(wv*48 + 32 + llo)*C_SZ + lhi*8];

  float4 n0, n1, n2, n3;
#define LOADX(T) { const float* p = xs + (T)*64; \
    n0 = *reinterpret_cast<const float4*>(p); \
    n1 = *reinterpret_cast<const float4*>(p + 4); \
    n2 = *reinterpret_cast<const float4*>(p + 8); \
    n3 = *reinterpret_cast<const float4*>(p + 12); }
#define STAGE_WRITE(BUF) { int bb = (BUF)*1024; short4v w; \
    w[0]=f2bs(n0.x); w[1]=f2bs(n0.y); w[2]=f2bs(n0.z); w[3]=f2bs(n0.w); \
    *reinterpret_cast<short4v*>(&myA[bb + wo0])     = w; \
    w[0]=f2bs(n1.x); w[1]=f2bs(n1.y); w[2]=f2bs(n1.z); w[3]=f2bs(n1.w); \
    *reinterpret_cast<short4v*>(&myA[bb + wo0 + 4]) = w; \
    w[0]=f2bs(n2.x); w[1]=f2bs(n2.y); w[2]=f2bs(n2.z); w[3]=f2bs(n2.w); \
    *reinterpret_cast<short4v*>(&myA[bb + wo1])     = w; \
    w[0]=f2bs(n3.x); w[1]=f2bs(n3.y); w[2]=f2bs(n3.z); w[3]=f2bs(n3.w); \
    *reinterpret_cast<short4v*>(&myA[bb + wo1 + 4]) = w; }

  bf16x8 bcur[6], bnxt[6];
  bcur[0] = *reinterpret_cast<const bf16x8*>(bp0);
  bcur[1] = *reinterpret_cast<const bf16x8*>(bp0 + 32);
  bcur[2] = *reinterpret_cast<const bf16x8*>(bp1);
  bcur[3] = *reinterpret_cast<const bf16x8*>(bp1 + 32);
  bcur[4] = *reinterpret_cast<const bf16x8*>(bp2);
  bcur[5] = *reinterpret_cast<const bf16x8*>(bp2 + 32);

  LOADX(0); STAGE_WRITE(0); LOADX(1);

  #pragma unroll
  for (int t = 0; t < 12; ++t){
    int cb = t & 1;
    bf16x8 af0 = *reinterpret_cast<const bf16x8*>(&myA[cb*1024 + ro0]);
    bf16x8 af1 = *reinterpret_cast<const bf16x8*>(&myA[cb*1024 + ro1]);
    if (t < 11){
      int ko = (t + 1)*64;
      bnxt[0] = *reinterpret_cast<const bf16x8*>(bp0 + ko);
      bnxt[1] = *reinterpret_cast<const bf16x8*>(bp0 + ko + 32);
      bnxt[2] = *reinterpret_cast<const bf16x8*>(bp1 + ko);
      bnxt[3] = *reinterpret_cast<const bf16x8*>(bp1 + ko + 32);
      bnxt[4] = *reinterpret_cast<const bf16x8*>(bp2 + ko);
      bnxt[5] = *reinterpret_cast<const bf16x8*>(bp2 + ko + 32);
      STAGE_WRITE(cb ^ 1);                  // regs hold tile t+1
    }
    if (t < 10) LOADX(t + 2);               // depth-2 x prefetch
    acc[0] = __builtin_amdgcn_mfma_f32_16x16x32_bf16(af0, bcur[0], acc[0], 0, 0, 0);
    acc[0] = __builtin_amdgcn_mfma_f32_16x16x32_bf16(af1, bcur[1], acc[0], 0, 0, 0);
    acc[1] = __builtin_amdgcn_mfma_f32_16x16x32_bf16(af0, bcur[2], acc[1], 0, 0, 0);
    acc[1] = __builtin_amdgcn_mfma_f32_16x16x32_bf16(af1, bcur[3], acc[1], 0, 0, 0);
    acc[2] = __builtin_amdgcn_mfma_f32_16x16x32_bf16(af0, bcur[4], acc[2], 0, 0, 0);
    acc[2] = __builtin_amdgcn_mfma_f32_16x16x32_bf16(af1, bcur[5], acc[2], 0, 0, 0);
    #pragma unroll
    for (int u = 0; u < 6; ++u) bcur[u] = bnxt[u];  // renamed away by full unroll
  }
#undef LOADX
#undef STAGE_WRITE

  long mbase = R0 + lhi*4;
  #pragma unroll
  for (int j = 0; j < 3; ++j){
    int n = wv*48 + j*16 + llo;
    int mat = n >> 6, c = n & 63;
    if (mat == 2){
      long b = mbase >> 11, t = mbase & 2047;
      short4v p;
      #pragma unroll
      for (int reg = 0; reg < 4; ++reg) p[reg] = f2bs(acc[j][reg]);
      *reinterpret_cast<short4v*>(&vT[(b*H_SZ + c)*T_SZ + t]) = p;
    } else {
      short* dst = (mat == 0) ? qb : kb;
      #pragma unroll
      for (int reg = 0; reg < 4; ++reg)
        dst[(mbase + reg)*H_SZ + c] = f2bs(acc[j][reg]);
    }
  }
}

// --- K2: flash attention, XCD-batch-affinity swizzle, swapped QK^T, log2 softmax, defer-max ---
__global__ __launch_bounds__(512, 2) void attn_fwd(const short* __restrict__ qb, const short* __restrict__ kb,
                        const short* __restrict__ vT, const float* __restrict__ bsc,
                        float* __restrict__ out){
  __shared__ float bias_s[2048];            // 8 KB
  __shared__ float pool[8][1040];           // per-wave 4160B: P tile (16x72 shorts) in loop, o_part (16x65 f32) after
  __shared__ float m_part[8][16];
  __shared__ float l_part[8][16];

  int tid = threadIdx.x;
  for (int i = tid; i < 2048; i += 512) bias_s[i] = bsc[i];

  int wv = tid >> 6, lane = tid & 63, lhi = lane >> 4, llo = lane & 15;
  int g = wv >> 2, ws = wv & 3;
  int b = blockIdx.x & 7, jj = blockIdx.x >> 3;   // batch -> XCD affinity: K/V stay L2-resident
  int qt = g ? (127 - jj) : jj;
  int q0 = qt * 16;
  int q = q0 + llo;

  const short* qrow = &qb[((long)(b*T_SZ + q))*H_SZ + lhi*8];
  bf16x8 qf0 = *reinterpret_cast<const bf16x8*>(qrow);
  bf16x8 qf1 = *reinterpret_cast<const bf16x8*>(qrow + 32);
  const short* kbase = kb + (long)b*T_SZ*H_SZ;
  const short* vbase = vT + (long)b*H_SZ*T_SZ;
  short* Pw = (short*)&pool[wv][0];         // 16 rows x 72 shorts
  __syncthreads();

  float m_r = -1e30f, l_r = 0.f;
  f32x4 o[4];
  #pragma unroll
  for (int df = 0; df < 4; ++df) o[df] = (f32x4){0.f,0.f,0.f,0.f};

  int nkt = (qt >> 2) + 1;
  for (int kt = ws; kt < nkt; kt += 4){
    int kv0 = kt * 64;
    bf16x8 kf0[4], kf1[4];
    #pragma unroll
    for (int f = 0; f < 4; ++f){
      const short* kr = kbase + (long)(kv0 + f*16 + llo)*H_SZ + lhi*8;
      kf0[f] = *reinterpret_cast<const bf16x8*>(kr);
      kf1[f] = *reinterpret_cast<const bf16x8*>(kr + 32);
    }
    f32x4 s[4];
    #pragma unroll
    for (int f = 0; f < 4; ++f){            // S^T = K.Q^T: lane holds S[kv][q=llo]
      f32x4 t = (f32x4){0.f,0.f,0.f,0.f};
      t = __builtin_amdgcn_mfma_f32_16x16x32_bf16(kf0[f], qf0, t, 0, 0, 0);
      t = __builtin_amdgcn_mfma_f32_16x16x32_bf16(kf1[f], qf1, t, 0, 0, 0);
      s[f] = t;
    }
    // issue V loads now — latency flies over softmax
    bf16x8 vf0[4], vf1[4];
    #pragma unroll
    for (int d = 0; d < 4; ++d){
      const short* vr = vbase + (long)(d*16 + llo)*T_SZ + kv0 + lhi*8;
      vf0[d] = *reinterpret_cast<const bf16x8*>(vr);
      vf1[d] = *reinterpret_cast<const bf16x8*>(vr + 32);
    }
    // bias + causal mask, log2 domain (0.125 * log2e)
    #pragma unroll
    for (int f = 0; f < 4; ++f)
      #pragma unroll
      for (int rg = 0; rg < 4; ++rg){
        int kv = kv0 + f*16 + lhi*4 + rg;
        int rel = q - kv;
        float bv = bias_s[rel > 0 ? rel : 0];
        s[f][rg] = (rel >= 0) ? fmaf(s[f][rg], 0.18033688f, bv) : -1e30f;
      }
    f32x4 tm = vmax4(vmax4(s[0], s[1]), vmax4(s[2], s[3]));
    float pmax = fmaxf(fmaxf(tm[0], tm[1]), fmaxf(tm[2], tm[3]));
    pmax = fmaxf(pmax, __shfl_xor(pmax, 16));
    pmax = fmaxf(pmax, __shfl_xor(pmax, 32));
    bool keep = __all(pmax <= m_r + 8.0f);  // defer-max: P bounded by 2^8
    if (!keep){
      float mnew = fmaxf(m_r, pmax);
      float corr = exp2f(m_r - mnew);
      m_r = mnew;
      l_r *= corr;
      #pragma unroll
      for (int df = 0; df < 4; ++df) o[df] = o[df] * corr;
    }
    #pragma unroll
    for (int f = 0; f < 4; ++f)
      #pragma unroll
      for (int rg = 0; rg < 4; ++rg)
        s[f][rg] = exp2f(s[f][rg] - m_r);
    f32x4 va = (s[0] + s[1]) + (s[2] + s[3]);
    float rs = (va[0] + va[1]) + (va[2] + va[3]);
    rs += __shfl_xor(rs, 16);
    rs += __shfl_xor(rs, 32);
    l_r += rs;
    // P^T -> LDS [q=llo][kv] -> B-frags
    #pragma unroll
    for (int f = 0; f < 4; ++f){
      short4v pk;
      #pragma unroll
      for (int rg = 0; rg < 4; ++rg) pk[rg] = f2bs(s[f][rg]);
      *reinterpret_cast<short4v*>(&Pw[llo*72 + f*16 + lhi*4]) = pk;
    }
    bf16x8 pb0 = *reinterpret_cast<const bf16x8*>(&Pw[llo*72 + lhi*8]);
    bf16x8 pb1 = *reinterpret_cast<const bf16x8*>(&Pw[llo*72 + 32 + lhi*8]);
    #pragma unroll
    for (int df = 0; df < 4; ++df){         // O^T = V^T.P^T
      o[df] = __builtin_amdgcn_mfma_f32_16x16x32_bf16(vf0[df], pb0, o[df], 0, 0, 0);
      o[df] = __builtin_amdgcn_mfma_f32_16x16x32_bf16(vf1[df], pb1, o[df], 0, 0, 0);
    }
  }

  // flash partials -> pool (reuses P region; wave-local, program-order safe)
  #pragma unroll
  for (int df = 0; df < 4; ++df)
    #pragma unroll
    for (int rg = 0; rg < 4; ++rg)
      pool[wv][llo*65 + df*16 + lhi*4 + rg] = o[df][rg];
  if (lhi == 0){ m_part[wv][llo] = m_r; l_part[wv][llo] = l_r; }
  __syncthreads();

  // merge 4 partials per group; 512 threads cover both groups' 16x64 outputs
  int g2 = tid >> 8, r2 = tid & 255;
  int d = r2 & 63, q4 = r2 >> 6;
  int qt2 = g2 ? (127 - jj) : jj;
  long obase = ((long)(b*T_SZ + qt2*16))*H_SZ;
  #pragma unroll
  for (int i = 0; i < 4; ++i){
    int qq = q4*4 + i;
    float mstar = m_part[g2*4][qq];
    #pragma unroll
    for (int w = 1; w < 4; ++w) mstar = fmaxf(mstar, m_part[g2*4 + w][qq]);
    float lsum = 0.f, osum = 0.f;
    #pragma unroll
    for (int w = 0; w < 4; ++w){
      float sc = exp2f(m_part[g2*4 + w][qq] - mstar);
      lsum += l_part[g2*4 + w][qq] * sc;
      osum += pool[g2*4 + w][qq*65 + d] * sc;
    }
    out[obase + (long)qq*H_SZ + d] = osum / lsum;
  }
}

extern "C" void kernel_launch(void* const* d_in, const int* in_sizes, int n_in,
                              void* d_out, int out_size, void* d_ws, size_t ws_size,
                              hipStream_t stream){
  const float* x    = (const float*)d_in[0];
  const float* Wq   = (const float*)d_in[1];
  const float* Wk   = (const float*)d_in[2];
  const float* Wv   = (const float*)d_in[3];
  const float* bias = (const float*)d_in[4];
  float* out = (float*)d_out;

  const size_t NTOK = (size_t)B_SZ * T_SZ * H_SZ;   // 1,048,576
  short* qb = (short*)d_ws;
  short* kb = qb + NTOK;
  short* vT = kb + NTOK;
  short* Wt = vT + NTOK;                            // 192*768 shorts
  float* bsc = (float*)(Wt + 192*C_SZ);             // 2048 floats

  prep_wt<<<44, 256, 0, stream>>>(Wq, Wk, Wv, bias, Wt, bsc);
  qkv_gemm<<<1024, 256, 0, stream>>>(x, Wt, qb, kb, vT);
  attn_fwd<<<512, 512, 0, stream>>>(qb, kb, vT, bsc, out);
}

// Round 6
// 83.097 us; speedup vs baseline: 1.3263x; 1.1072x over previous
//
#include <hip/hip_runtime.h>
#include <hip/hip_bf16.h>

typedef __attribute__((ext_vector_type(8))) short bf16x8;
typedef __attribute__((ext_vector_type(4))) short short4v;
typedef __attribute__((ext_vector_type(4))) float f32x4;

#define B_SZ 8
#define T_SZ 2048
#define C_SZ 768
#define H_SZ 64

__device__ __forceinline__ short f2bs(float f){
  __hip_bfloat16 h = __float2bfloat16(f);
  short s; __builtin_memcpy(&s, &h, 2); return s;
}
__device__ __forceinline__ f32x4 vmax4(f32x4 a, f32x4 b){
  f32x4 r; r[0]=fmaxf(a[0],b[0]); r[1]=fmaxf(a[1],b[1]);
  r[2]=fmaxf(a[2],b[2]); r[3]=fmaxf(a[3],b[3]); return r;
}
// async global->LDS, 16B/lane; dest = lds_base + lane*16 (wave-linear), cannot be sunk
__device__ __forceinline__ void gload16(const float* g, float* l){
  __builtin_amdgcn_global_load_lds(
    (const __attribute__((address_space(1))) unsigned int*)g,
    (__attribute__((address_space(3))) unsigned int*)l, 16, 0, 0);
}

// --- K0: Wt transpose (blocks 0-35) + log2-scaled bias table (blocks 36-43) ---
__global__ __launch_bounds__(256) void prep_wt(const float* __restrict__ Wq, const float* __restrict__ Wk,
                        const float* __restrict__ Wv, const float* __restrict__ bias,
                        short* __restrict__ Wt, float* __restrict__ bsc){
  int tid = threadIdx.x;
  if (blockIdx.x >= 36){
    int i = (blockIdx.x - 36)*256 + tid;
    bsc[i] = bias[i] * 1.44269504f;         // log2e — softmax in exp2 domain
    return;
  }
  __shared__ float tile[64][65];
  int mat = blockIdx.x / 12, kblk = blockIdx.x % 12;
  const float* W = (mat == 0) ? Wq : (mat == 1 ? Wk : Wv);
  int k0 = kblk * 64;
  int r = tid >> 2, cq = (tid & 3) * 16;
  #pragma unroll
  for (int i = 0; i < 4; ++i){
    float4 v = *reinterpret_cast<const float4*>(&W[(k0 + r)*H_SZ + cq + i*4]);
    tile[r][cq + i*4 + 0] = v.x; tile[r][cq + i*4 + 1] = v.y;
    tile[r][cq + i*4 + 2] = v.z; tile[r][cq + i*4 + 3] = v.w;
  }
  __syncthreads();
  int n = tid >> 2, kq = (tid & 3) * 16;
  bf16x8 o0, o1;
  #pragma unroll
  for (int e = 0; e < 8; ++e){
    o0[e] = f2bs(tile[kq + e][n]);
    o1[e] = f2bs(tile[kq + 8 + e][n]);
  }
  *reinterpret_cast<bf16x8*>(&Wt[(mat*64 + n)*C_SZ + k0 + kq])     = o0;
  *reinterpret_cast<bf16x8*>(&Wt[(mat*64 + n)*C_SZ + k0 + kq + 8]) = o1;
}

// --- K1: QKV GEMM, m97-style: async fp32 A-stage via global_load_lds (XOR-swizzled
//     source), double-buffered + barrier per k-step; B direct from L2-hot Wt.
//     BM=32, BN=192, BK=64; 512 blocks x 8 waves (2 row-groups x 4 col-groups) ---
__global__ __launch_bounds__(512, 2) void qkv_gemm(const float* __restrict__ x, const short* __restrict__ Wt,
                         short* __restrict__ qb, short* __restrict__ kb, short* __restrict__ vT){
  __shared__ float As[2][2048];             // 2 bufs x (32 rows x 64 floats) = 16 KB
  int tid = threadIdx.x;
  int wv = tid >> 6, lane = tid & 63, lhi = lane >> 4, llo = lane & 15;
  int wm = wv >> 2, wn = wv & 3;
  long R0 = (long)blockIdx.x * 32;

  // stage geometry: thread t covers LDS bytes [t*16, t*16+16): row = t/16, slot-chunk = t%16.
  // source chunk = slot ^ (row&7)  (involution; read side applies the same XOR)
  int srow = tid >> 4;
  int schunk = (tid & 15) ^ (srow & 7);
  const float* gsrc = &x[(R0 + srow)*C_SZ + schunk*4];
  float* ldst = &As[0][wv*256];             // wave-uniform base (lane*16B appended by HW)

  f32x4 acc[3];
  #pragma unroll
  for (int j = 0; j < 3; ++j) acc[j] = (f32x4){0.f,0.f,0.f,0.f};

  // A-frag read offsets (floats within row), XOR-swizzled
  int rr = wm*16 + llo;
  int r7 = rr & 7, lhi2 = lhi*2;
  int c0 = ((lhi2    ) ^ r7) << 2;
  int c1 = ((lhi2 + 1) ^ r7) << 2;
  int c2 = ((lhi2 + 8) ^ r7) << 2;
  int c3 = ((lhi2 + 9) ^ r7) << 2;

  gload16(gsrc, ldst);                      // tile 0 -> buf 0
  __syncthreads();

  for (int t = 0; t < 12; ++t){
    int cb = t & 1;
    if (t < 11) gload16(gsrc + (t + 1)*64, ldst + (cb ^ 1)*2048);  // async prefetch
    const float* Ar = &As[cb][rr*64];
    f32x4 a0 = *reinterpret_cast<const f32x4*>(Ar + c0);
    f32x4 a1 = *reinterpret_cast<const f32x4*>(Ar + c1);
    f32x4 a2 = *reinterpret_cast<const f32x4*>(Ar + c2);
    f32x4 a3 = *reinterpret_cast<const f32x4*>(Ar + c3);
    bf16x8 af0, af1;
    #pragma unroll
    for (int e = 0; e < 4; ++e){
      af0[e]   = f2bs(a0[e]); af0[4+e] = f2bs(a1[e]);
      af1[e]   = f2bs(a2[e]); af1[4+e] = f2bs(a3[e]);
    }
    int k0 = t*64;
    #pragma unroll
    for (int j = 0; j < 3; ++j){
      const short* bp = &Wt[(wn*48 + j*16 + llo)*C_SZ + k0 + lhi*8];
      bf16x8 b0 = *reinterpret_cast<const bf16x8*>(bp);
      bf16x8 b1 = *reinterpret_cast<const bf16x8*>(bp + 32);
      acc[j] = __builtin_amdgcn_mfma_f32_16x16x32_bf16(af0, b0, acc[j], 0, 0, 0);
      acc[j] = __builtin_amdgcn_mfma_f32_16x16x32_bf16(af1, b1, acc[j], 0, 0, 0);
    }
    __syncthreads();                        // drains prefetch (ready for t+1), syncs LDS reuse
  }

  long mbase = R0 + wm*16 + lhi*4;
  #pragma unroll
  for (int j = 0; j < 3; ++j){
    int n = wn*48 + j*16 + llo;
    int mat = n >> 6, c = n & 63;
    if (mat == 2){
      long b = mbase >> 11, t = mbase & 2047;
      short4v p;
      #pragma unroll
      for (int reg = 0; reg < 4; ++reg) p[reg] = f2bs(acc[j][reg]);
      *reinterpret_cast<short4v*>(&vT[(b*H_SZ + c)*T_SZ + t]) = p;
    } else {
      short* dst = (mat == 0) ? qb : kb;
      #pragma unroll
      for (int reg = 0; reg < 4; ++reg)
        dst[(mbase + reg)*H_SZ + c] = f2bs(acc[j][reg]);
    }
  }
}

// --- K2: flash attention, XCD-batch-affinity swizzle, swapped QK^T, log2 softmax, defer-max ---
__global__ __launch_bounds__(512, 2) void attn_fwd(const short* __restrict__ qb, const short* __restrict__ kb,
                        const short* __restrict__ vT, const float* __restrict__ bsc,
                        float* __restrict__ out){
  __shared__ float bias_s[2048];            // 8 KB
  __shared__ float pool[8][1040];           // per-wave: P tile (16x72 shorts) in loop, o_part (16x65 f32) after
  __shared__ float m_part[8][16];
  __shared__ float l_part[8][16];

  int tid = threadIdx.x;
  for (int i = tid; i < 2048; i += 512) bias_s[i] = bsc[i];

  int wv = tid >> 6, lane = tid & 63, lhi = lane >> 4, llo = lane & 15;
  int g = wv >> 2, ws = wv & 3;
  int b = blockIdx.x & 7, jj = blockIdx.x >> 3;   // batch -> XCD affinity: K/V stay L2-resident
  int qt = g ? (127 - jj) : jj;
  int q0 = qt * 16;
  int q = q0 + llo;

  const short* qrow = &qb[((long)(b*T_SZ + q))*H_SZ + lhi*8];
  bf16x8 qf0 = *reinterpret_cast<const bf16x8*>(qrow);
  bf16x8 qf1 = *reinterpret_cast<const bf16x8*>(qrow + 32);
  const short* kbase = kb + (long)b*T_SZ*H_SZ;
  const short* vbase = vT + (long)b*H_SZ*T_SZ;
  short* Pw = (short*)&pool[wv][0];         // 16 rows x 72 shorts
  __syncthreads();

  float m_r = -1e30f, l_r = 0.f;
  f32x4 o[4];
  #pragma unroll
  for (int df = 0; df < 4; ++df) o[df] = (f32x4){0.f,0.f,0.f,0.f};

  int nkt = (qt >> 2) + 1;
  for (int kt = ws; kt < nkt; kt += 4){
    int kv0 = kt * 64;
    bf16x8 kf0[4], kf1[4];
    #pragma unroll
    for (int f = 0; f < 4; ++f){
      const short* kr = kbase + (long)(kv0 + f*16 + llo)*H_SZ + lhi*8;
      kf0[f] = *reinterpret_cast<const bf16x8*>(kr);
      kf1[f] = *reinterpret_cast<const bf16x8*>(kr + 32);
    }
    f32x4 s[4];
    #pragma unroll
    for (int f = 0; f < 4; ++f){            // S^T = K.Q^T: lane holds S[kv][q=llo]
      f32x4 t = (f32x4){0.f,0.f,0.f,0.f};
      t = __builtin_amdgcn_mfma_f32_16x16x32_bf16(kf0[f], qf0, t, 0, 0, 0);
      t = __builtin_amdgcn_mfma_f32_16x16x32_bf16(kf1[f], qf1, t, 0, 0, 0);
      s[f] = t;
    }
    // issue V loads now — latency flies over softmax
    bf16x8 vf0[4], vf1[4];
    #pragma unroll
    for (int d = 0; d < 4; ++d){
      const short* vr = vbase + (long)(d*16 + llo)*T_SZ + kv0 + lhi*8;
      vf0[d] = *reinterpret_cast<const bf16x8*>(vr);
      vf1[d] = *reinterpret_cast<const bf16x8*>(vr + 32);
    }
    // bias + causal mask, log2 domain (0.125 * log2e)
    #pragma unroll
    for (int f = 0; f < 4; ++f)
      #pragma unroll
      for (int rg = 0; rg < 4; ++rg){
        int kv = kv0 + f*16 + lhi*4 + rg;
        int rel = q - kv;
        float bv = bias_s[rel > 0 ? rel : 0];
        s[f][rg] = (rel >= 0) ? fmaf(s[f][rg], 0.18033688f, bv) : -1e30f;
      }
    f32x4 tm = vmax4(vmax4(s[0], s[1]), vmax4(s[2], s[3]));
    float pmax = fmaxf(fmaxf(tm[0], tm[1]), fmaxf(tm[2], tm[3]));
    pmax = fmaxf(pmax, __shfl_xor(pmax, 16));
    pmax = fmaxf(pmax, __shfl_xor(pmax, 32));
    bool keep = __all(pmax <= m_r + 8.0f);  // defer-max: P bounded by 2^8
    if (!keep){
      float mnew = fmaxf(m_r, pmax);
      float corr = exp2f(m_r - mnew);
      m_r = mnew;
      l_r *= corr;
      #pragma unroll
      for (int df = 0; df < 4; ++df) o[df] = o[df] * corr;
    }
    #pragma unroll
    for (int f = 0; f < 4; ++f)
      #pragma unroll
      for (int rg = 0; rg < 4; ++rg)
        s[f][rg] = exp2f(s[f][rg] - m_r);
    f32x4 va = (s[0] + s[1]) + (s[2] + s[3]);
    float rs = (va[0] + va[1]) + (va[2] + va[3]);
    rs += __shfl_xor(rs, 16);
    rs += __shfl_xor(rs, 32);
    l_r += rs;
    // P^T -> LDS [q=llo][kv] -> B-frags
    #pragma unroll
    for (int f = 0; f < 4; ++f){
      short4v pk;
      #pragma unroll
      for (int rg = 0; rg < 4; ++rg) pk[rg] = f2bs(s[f][rg]);
      *reinterpret_cast<short4v*>(&Pw[llo*72 + f*16 + lhi*4]) = pk;
    }
    bf16x8 pb0 = *reinterpret_cast<const bf16x8*>(&Pw[llo*72 + lhi*8]);
    bf16x8 pb1 = *reinterpret_cast<const bf16x8*>(&Pw[llo*72 + 32 + lhi*8]);
    #pragma unroll
    for (int df = 0; df < 4; ++df){         // O^T = V^T.P^T
      o[df] = __builtin_amdgcn_mfma_f32_16x16x32_bf16(vf0[df], pb0, o[df], 0, 0, 0);
      o[df] = __builtin_amdgcn_mfma_f32_16x16x32_bf16(vf1[df], pb1, o[df], 0, 0, 0);
    }
  }

  // flash partials -> pool (reuses P region; wave-local, program-order safe)
  #pragma unroll
  for (int df = 0; df < 4; ++df)
    #pragma unroll
    for (int rg = 0; rg < 4; ++rg)
      pool[wv][llo*65 + df*16 + lhi*4 + rg] = o[df][rg];
  if (lhi == 0){ m_part[wv][llo] = m_r; l_part[wv][llo] = l_r; }
  __syncthreads();

  // merge 4 partials per group; 512 threads cover both groups' 16x64 outputs
  int g2 = tid >> 8, r2 = tid & 255;
  int d = r2 & 63, q4 = r2 >> 6;
  int qt2 = g2 ? (127 - jj) : jj;
  long obase = ((long)(b*T_SZ + qt2*16))*H_SZ;
  #pragma unroll
  for (int i = 0; i < 4; ++i){
    int qq = q4*4 + i;
    float mstar = m_part[g2*4][qq];
    #pragma unroll
    for (int w = 1; w < 4; ++w) mstar = fmaxf(mstar, m_part[g2*4 + w][qq]);
    float lsum = 0.f, osum = 0.f;
    #pragma unroll
    for (int w = 0; w < 4; ++w){
      float sc = exp2f(m_part[g2*4 + w][qq] - mstar);
      lsum += l_part[g2*4 + w][qq] * sc;
      osum += pool[g2*4 + w][qq*65 + d] * sc;
    }
    out[obase + (long)qq*H_SZ + d] = osum / lsum;
  }
}

extern "C" void kernel_launch(void* const* d_in, const int* in_sizes, int n_in,
                              void* d_out, int out_size, void* d_ws, size_t ws_size,
                              hipStream_t stream){
  const float* x    = (const float*)d_in[0];
  const float* Wq   = (const float*)d_in[1];
  const float* Wk   = (const float*)d_in[2];
  const float* Wv   = (const float*)d_in[3];
  const float* bias = (const float*)d_in[4];
  float* out = (float*)d_out;

  const size_t NTOK = (size_t)B_SZ * T_SZ * H_SZ;   // 1,048,576
  short* qb = (short*)d_ws;
  short* kb = qb + NTOK;
  short* vT = kb + NTOK;
  short* Wt = vT + NTOK;                            // 192*768 shorts
  float* bsc = (float*)(Wt + 192*C_SZ);             // 2048 floats

  prep_wt<<<44, 256, 0, stream>>>(Wq, Wk, Wv, bias, Wt, bsc);
  qkv_gemm<<<512, 512, 0, stream>>>(x, Wt, qb, kb, vT);
  attn_fwd<<<512, 512, 0, stream>>>(qb, kb, vT, bsc, out);
}

// Round 7
// 62.322 us; speedup vs baseline: 1.7684x; 1.3334x over previous
//
#include <hip/hip_runtime.h>
#include <hip/hip_bf16.h>

typedef __attribute__((ext_vector_type(8))) short bf16x8;
typedef __attribute__((ext_vector_type(4))) short short4v;
typedef __attribute__((ext_vector_type(4))) float f32x4;

#define B_SZ 8
#define T_SZ 2048
#define C_SZ 768
#define H_SZ 64

__device__ __forceinline__ short f2bs(float f){
  __hip_bfloat16 h = __float2bfloat16(f);
  short s; __builtin_memcpy(&s, &h, 2); return s;
}
__device__ __forceinline__ f32x4 vmax4(f32x4 a, f32x4 b){
  f32x4 r; r[0]=fmaxf(a[0],b[0]); r[1]=fmaxf(a[1],b[1]);
  r[2]=fmaxf(a[2],b[2]); r[3]=fmaxf(a[3],b[3]); return r;
}
// async global->LDS, 16B/lane; dest = wave-uniform base + lane*16; unsinkable by compiler
__device__ __forceinline__ void gload16(const void* g, void* l){
  __builtin_amdgcn_global_load_lds(
    (const __attribute__((address_space(1))) unsigned int*)g,
    (__attribute__((address_space(3))) unsigned int*)l, 16, 0, 0);
}

// --- K0: Wt transpose (blocks 0-35) + log2-scaled bias table (blocks 36-43) ---
__global__ __launch_bounds__(256) void prep_wt(const float* __restrict__ Wq, const float* __restrict__ Wk,
                        const float* __restrict__ Wv, const float* __restrict__ bias,
                        short* __restrict__ Wt, float* __restrict__ bsc){
  int tid = threadIdx.x;
  if (blockIdx.x >= 36){
    int i = (blockIdx.x - 36)*256 + tid;
    bsc[i] = bias[i] * 1.44269504f;         // log2e — softmax in exp2 domain
    return;
  }
  __shared__ float tile[64][65];
  int mat = blockIdx.x / 12, kblk = blockIdx.x % 12;
  const float* W = (mat == 0) ? Wq : (mat == 1 ? Wk : Wv);
  int k0 = kblk * 64;
  int r = tid >> 2, cq = (tid & 3) * 16;
  #pragma unroll
  for (int i = 0; i < 4; ++i){
    float4 v = *reinterpret_cast<const float4*>(&W[(k0 + r)*H_SZ + cq + i*4]);
    tile[r][cq + i*4 + 0] = v.x; tile[r][cq + i*4 + 1] = v.y;
    tile[r][cq + i*4 + 2] = v.z; tile[r][cq + i*4 + 3] = v.w;
  }
  __syncthreads();
  int n = tid >> 2, kq = (tid & 3) * 16;
  bf16x8 o0, o1;
  #pragma unroll
  for (int e = 0; e < 8; ++e){
    o0[e] = f2bs(tile[kq + e][n]);
    o1[e] = f2bs(tile[kq + 8 + e][n]);
  }
  *reinterpret_cast<bf16x8*>(&Wt[(mat*64 + n)*C_SZ + k0 + kq])     = o0;
  *reinterpret_cast<bf16x8*>(&Wt[(mat*64 + n)*C_SZ + k0 + kq + 8]) = o1;
}

// --- K1: QKV GEMM, BOTH A and B async-staged via global_load_lds, double-buffered,
//     one barrier per k-step. BM=32, BN=192, BK=64; 512 blocks x 8 waves ---
__global__ __launch_bounds__(512, 2) void qkv_gemm(const float* __restrict__ x, const short* __restrict__ Wt,
                         short* __restrict__ qb, short* __restrict__ kb, short* __restrict__ vT){
  __shared__ float As[2][2048];             // 16 KB: 32 rows x 64 fp32, chunk16-swizzled
  __shared__ short Bs[2][12288];            // 48 KB: 192 rows x 64 bf16, chunk16-swizzled
  int tid = threadIdx.x;
  int wv = tid >> 6, lane = tid & 63, lhi = lane >> 4, llo = lane & 15;
  int wm = wv >> 2, wn = wv & 3;
  long R0 = (long)blockIdx.x * 32;

  // ---- A staging: thread t covers LDS bytes [t*16, t*16+16): row = t/16, chunk = t%16.
  // source chunk = chunk ^ (row&7) (involution; read applies same XOR)
  int srow = tid >> 4;
  int schunk = (tid & 15) ^ (srow & 7);
  const float* gsrcA = &x[(R0 + srow)*C_SZ + schunk*4];
  float* ldstA = &As[0][wv*256];            // wave-uniform base

  // ---- B staging: 3 sections of 8KB; section p: rows p*64+(t>>3), chunk = t&7,
  // source chunk = (t&7) ^ ((t>>3)&7)
  int bn = tid >> 3;                        // row within section (0..63)
  int bc = (tid & 7) ^ (bn & 7);            // swizzled source chunk
  const short* gsrcB0 = &Wt[(  0 + bn)*C_SZ + bc*8];
  const short* gsrcB1 = &Wt[( 64 + bn)*C_SZ + bc*8];
  const short* gsrcB2 = &Wt[(128 + bn)*C_SZ + bc*8];
  short* ldstB = &Bs[0][wv*512];            // wave-uniform base (within each 8KB section)

  f32x4 acc[3];
  #pragma unroll
  for (int j = 0; j < 3; ++j) acc[j] = (f32x4){0.f,0.f,0.f,0.f};

  // A-frag read offsets (floats), XOR-swizzled
  int rr = wm*16 + llo;
  int r7 = rr & 7, lhi2 = lhi*2;
  int c0 = ((lhi2    ) ^ r7) << 2;
  int c1 = ((lhi2 + 1) ^ r7) << 2;
  int c2 = ((lhi2 + 8) ^ r7) << 2;
  int c3 = ((lhi2 + 9) ^ r7) << 2;
  // B-frag read offsets (shorts), XOR-swizzled: row n, k-chunk ks*4+lhi
  int nrow[3];
  #pragma unroll
  for (int j = 0; j < 3; ++j) nrow[j] = (wn*48 + j*16 + llo)*64;
  int llo7 = llo & 7;
  int bo0 = ((    lhi) ^ llo7)*8;           // ks=0
  int bo1 = ((4 + lhi) ^ llo7)*8;           // ks=1

#define STAGE(T, BUF) { \
    gload16(gsrcA  + (T)*64, ldstA + (BUF)*2048); \
    gload16(gsrcB0 + (T)*64, ldstB + (BUF)*12288); \
    gload16(gsrcB1 + (T)*64, ldstB + (BUF)*12288 + 4096); \
    gload16(gsrcB2 + (T)*64, ldstB + (BUF)*12288 + 8192); }

  STAGE(0, 0);
  __syncthreads();

  for (int t = 0; t < 12; ++t){
    int cb = t & 1;
    if (t < 11) STAGE(t + 1, cb ^ 1);       // async prefetch; drained by end-of-step barrier
    const float* Ar = &As[cb][rr*64];
    f32x4 a0 = *reinterpret_cast<const f32x4*>(Ar + c0);
    f32x4 a1 = *reinterpret_cast<const f32x4*>(Ar + c1);
    f32x4 a2 = *reinterpret_cast<const f32x4*>(Ar + c2);
    f32x4 a3 = *reinterpret_cast<const f32x4*>(Ar + c3);
    bf16x8 af0, af1;
    #pragma unroll
    for (int e = 0; e < 4; ++e){
      af0[e]   = f2bs(a0[e]); af0[4+e] = f2bs(a1[e]);
      af1[e]   = f2bs(a2[e]); af1[4+e] = f2bs(a3[e]);
    }
    const short* Br = &Bs[cb][0];
    #pragma unroll
    for (int j = 0; j < 3; ++j){
      bf16x8 b0 = *reinterpret_cast<const bf16x8*>(Br + nrow[j] + bo0);
      bf16x8 b1 = *reinterpret_cast<const bf16x8*>(Br + nrow[j] + bo1);
      acc[j] = __builtin_amdgcn_mfma_f32_16x16x32_bf16(af0, b0, acc[j], 0, 0, 0);
      acc[j] = __builtin_amdgcn_mfma_f32_16x16x32_bf16(af1, b1, acc[j], 0, 0, 0);
    }
    __syncthreads();                        // drains prefetch + syncs LDS buffer reuse
  }
#undef STAGE

  long mbase = R0 + wm*16 + lhi*4;
  #pragma unroll
  for (int j = 0; j < 3; ++j){
    int n = wn*48 + j*16 + llo;
    int mat = n >> 6, c = n & 63;
    if (mat == 2){
      long b = mbase >> 11, t = mbase & 2047;
      short4v p;
      #pragma unroll
      for (int reg = 0; reg < 4; ++reg) p[reg] = f2bs(acc[j][reg]);
      *reinterpret_cast<short4v*>(&vT[(b*H_SZ + c)*T_SZ + t]) = p;
    } else {
      short* dst = (mat == 0) ? qb : kb;
      #pragma unroll
      for (int reg = 0; reg < 4; ++reg)
        dst[(mbase + reg)*H_SZ + c] = f2bs(acc[j][reg]);
    }
  }
}

// --- K2: flash attention, XCD-batch-affinity swizzle, swapped QK^T, log2 softmax, defer-max ---
__global__ __launch_bounds__(512, 2) void attn_fwd(const short* __restrict__ qb, const short* __restrict__ kb,
                        const short* __restrict__ vT, const float* __restrict__ bsc,
                        float* __restrict__ out){
  __shared__ float bias_s[2048];            // 8 KB
  __shared__ float pool[8][1040];           // per-wave: P tile (16x72 shorts) in loop, o_part (16x65 f32) after
  __shared__ float m_part[8][16];
  __shared__ float l_part[8][16];

  int tid = threadIdx.x;
  for (int i = tid; i < 2048; i += 512) bias_s[i] = bsc[i];

  int wv = tid >> 6, lane = tid & 63, lhi = lane >> 4, llo = lane & 15;
  int g = wv >> 2, ws = wv & 3;
  int b = blockIdx.x & 7, jj = blockIdx.x >> 3;   // batch -> XCD affinity: K/V stay L2-resident
  int qt = g ? (127 - jj) : jj;
  int q0 = qt * 16;
  int q = q0 + llo;

  const short* qrow = &qb[((long)(b*T_SZ + q))*H_SZ + lhi*8];
  bf16x8 qf0 = *reinterpret_cast<const bf16x8*>(qrow);
  bf16x8 qf1 = *reinterpret_cast<const bf16x8*>(qrow + 32);
  const short* kbase = kb + (long)b*T_SZ*H_SZ;
  const short* vbase = vT + (long)b*H_SZ*T_SZ;
  short* Pw = (short*)&pool[wv][0];         // 16 rows x 72 shorts
  __syncthreads();

  float m_r = -1e30f, l_r = 0.f;
  f32x4 o[4];
  #pragma unroll
  for (int df = 0; df < 4; ++df) o[df] = (f32x4){0.f,0.f,0.f,0.f};

  int nkt = (qt >> 2) + 1;
  for (int kt = ws; kt < nkt; kt += 4){
    int kv0 = kt * 64;
    bf16x8 kf0[4], kf1[4];
    #pragma unroll
    for (int f = 0; f < 4; ++f){
      const short* kr = kbase + (long)(kv0 + f*16 + llo)*H_SZ + lhi*8;
      kf0[f] = *reinterpret_cast<const bf16x8*>(kr);
      kf1[f] = *reinterpret_cast<const bf16x8*>(kr + 32);
    }
    f32x4 s[4];
    #pragma unroll
    for (int f = 0; f < 4; ++f){            // S^T = K.Q^T: lane holds S[kv][q=llo]
      f32x4 t = (f32x4){0.f,0.f,0.f,0.f};
      t = __builtin_amdgcn_mfma_f32_16x16x32_bf16(kf0[f], qf0, t, 0, 0, 0);
      t = __builtin_amdgcn_mfma_f32_16x16x32_bf16(kf1[f], qf1, t, 0, 0, 0);
      s[f] = t;
    }
    // issue V loads now — latency flies over softmax
    bf16x8 vf0[4], vf1[4];
    #pragma unroll
    for (int d = 0; d < 4; ++d){
      const short* vr = vbase + (long)(d*16 + llo)*T_SZ + kv0 + lhi*8;
      vf0[d] = *reinterpret_cast<const bf16x8*>(vr);
      vf1[d] = *reinterpret_cast<const bf16x8*>(vr + 32);
    }
    // bias + causal mask, log2 domain (0.125 * log2e)
    #pragma unroll
    for (int f = 0; f < 4; ++f)
      #pragma unroll
      for (int rg = 0; rg < 4; ++rg){
        int kv = kv0 + f*16 + lhi*4 + rg;
        int rel = q - kv;
        float bv = bias_s[rel > 0 ? rel : 0];
        s[f][rg] = (rel >= 0) ? fmaf(s[f][rg], 0.18033688f, bv) : -1e30f;
      }
    f32x4 tm = vmax4(vmax4(s[0], s[1]), vmax4(s[2], s[3]));
    float pmax = fmaxf(fmaxf(tm[0], tm[1]), fmaxf(tm[2], tm[3]));
    pmax = fmaxf(pmax, __shfl_xor(pmax, 16));
    pmax = fmaxf(pmax, __shfl_xor(pmax, 32));
    bool keep = __all(pmax <= m_r + 8.0f);  // defer-max: P bounded by 2^8
    if (!keep){
      float mnew = fmaxf(m_r, pmax);
      float corr = exp2f(m_r - mnew);
      m_r = mnew;
      l_r *= corr;
      #pragma unroll
      for (int df = 0; df < 4; ++df) o[df] = o[df] * corr;
    }
    #pragma unroll
    for (int f = 0; f < 4; ++f)
      #pragma unroll
      for (int rg = 0; rg < 4; ++rg)
        s[f][rg] = exp2f(s[f][rg] - m_r);
    f32x4 va = (s[0] + s[1]) + (s[2] + s[3]);
    float rs = (va[0] + va[1]) + (va[2] + va[3]);
    rs += __shfl_xor(rs, 16);
    rs += __shfl_xor(rs, 32);
    l_r += rs;
    // P^T -> LDS [q=llo][kv] -> B-frags
    #pragma unroll
    for (int f = 0; f < 4; ++f){
      short4v pk;
      #pragma unroll
      for (int rg = 0; rg < 4; ++rg) pk[rg] = f2bs(s[f][rg]);
      *reinterpret_cast<short4v*>(&Pw[llo*72 + f*16 + lhi*4]) = pk;
    }
    bf16x8 pb0 = *reinterpret_cast<const bf16x8*>(&Pw[llo*72 + lhi*8]);
    bf16x8 pb1 = *reinterpret_cast<const bf16x8*>(&Pw[llo*72 + 32 + lhi*8]);
    #pragma unroll
    for (int df = 0; df < 4; ++df){         // O^T = V^T.P^T
      o[df] = __builtin_amdgcn_mfma_f32_16x16x32_bf16(vf0[df], pb0, o[df], 0, 0, 0);
      o[df] = __builtin_amdgcn_mfma_f32_16x16x32_bf16(vf1[df], pb1, o[df], 0, 0, 0);
    }
  }

  // flash partials -> pool (reuses P region; wave-local, program-order safe)
  #pragma unroll
  for (int df = 0; df < 4; ++df)
    #pragma unroll
    for (int rg = 0; rg < 4; ++rg)
      pool[wv][llo*65 + df*16 + lhi*4 + rg] = o[df][rg];
  if (lhi == 0){ m_part[wv][llo] = m_r; l_part[wv][llo] = l_r; }
  __syncthreads();

  // merge 4 partials per group; 512 threads cover both groups' 16x64 outputs
  int g2 = tid >> 8, r2 = tid & 255;
  int d = r2 & 63, q4 = r2 >> 6;
  int qt2 = g2 ? (127 - jj) : jj;
  long obase = ((long)(b*T_SZ + qt2*16))*H_SZ;
  #pragma unroll
  for (int i = 0; i < 4; ++i){
    int qq = q4*4 + i;
    float mstar = m_part[g2*4][qq];
    #pragma unroll
    for (int w = 1; w < 4; ++w) mstar = fmaxf(mstar, m_part[g2*4 + w][qq]);
    float lsum = 0.f, osum = 0.f;
    #pragma unroll
    for (int w = 0; w < 4; ++w){
      float sc = exp2f(m_part[g2*4 + w][qq] - mstar);
      lsum += l_part[g2*4 + w][qq] * sc;
      osum += pool[g2*4 + w][qq*65 + d] * sc;
    }
    out[obase + (long)qq*H_SZ + d] = osum / lsum;
  }
}

extern "C" void kernel_launch(void* const* d_in, const int* in_sizes, int n_in,
                              void* d_out, int out_size, void* d_ws, size_t ws_size,
                              hipStream_t stream){
  const float* x    = (const float*)d_in[0];
  const float* Wq   = (const float*)d_in[1];
  const float* Wk   = (const float*)d_in[2];
  const float* Wv   = (const float*)d_in[3];
  const float* bias = (const float*)d_in[4];
  float* out = (float*)d_out;

  const size_t NTOK = (size_t)B_SZ * T_SZ * H_SZ;   // 1,048,576
  short* qb = (short*)d_ws;
  short* kb = qb + NTOK;
  short* vT = kb + NTOK;
  short* Wt = vT + NTOK;                            // 192*768 shorts
  float* bsc = (float*)(Wt + 192*C_SZ);             // 2048 floats

  prep_wt<<<44, 256, 0, stream>>>(Wq, Wk, Wv, bias, Wt, bsc);
  qkv_gemm<<<512, 512, 0, stream>>>(x, Wt, qb, kb, vT);
  attn_fwd<<<512, 512, 0, stream>>>(qb, kb, vT, bsc, out);
}

// Round 8
// 58.354 us; speedup vs baseline: 1.8886x; 1.0680x over previous
//
#include <hip/hip_runtime.h>
#include <hip/hip_bf16.h>

typedef __attribute__((ext_vector_type(8))) short bf16x8;
typedef __attribute__((ext_vector_type(4))) short short4v;
typedef __attribute__((ext_vector_type(4))) float f32x4;

#define B_SZ 8
#define T_SZ 2048
#define C_SZ 768
#define H_SZ 64

__device__ __forceinline__ short f2bs(float f){
  __hip_bfloat16 h = __float2bfloat16(f);
  short s; __builtin_memcpy(&s, &h, 2); return s;
}
__device__ __forceinline__ f32x4 vmax4(f32x4 a, f32x4 b){
  f32x4 r; r[0]=fmaxf(a[0],b[0]); r[1]=fmaxf(a[1],b[1]);
  r[2]=fmaxf(a[2],b[2]); r[3]=fmaxf(a[3],b[3]); return r;
}
// async global->LDS, 16B/lane; dest = wave-uniform base + lane*16; unsinkable by compiler
__device__ __forceinline__ void gload16(const void* g, void* l){
  __builtin_amdgcn_global_load_lds(
    (const __attribute__((address_space(1))) unsigned int*)g,
    (__attribute__((address_space(3))) unsigned int*)l, 16, 0, 0);
}

// --- K0: Wt transpose (blocks 0-35) + log2-scaled bias table (blocks 36-43) ---
__global__ __launch_bounds__(256) void prep_wt(const float* __restrict__ Wq, const float* __restrict__ Wk,
                        const float* __restrict__ Wv, const float* __restrict__ bias,
                        short* __restrict__ Wt, float* __restrict__ bsc){
  int tid = threadIdx.x;
  if (blockIdx.x >= 36){
    int i = (blockIdx.x - 36)*256 + tid;
    bsc[i] = bias[i] * 1.44269504f;         // log2e — softmax in exp2 domain
    return;
  }
  __shared__ float tile[64][65];
  int mat = blockIdx.x / 12, kblk = blockIdx.x % 12;
  const float* W = (mat == 0) ? Wq : (mat == 1 ? Wk : Wv);
  int k0 = kblk * 64;
  int r = tid >> 2, cq = (tid & 3) * 16;
  #pragma unroll
  for (int i = 0; i < 4; ++i){
    float4 v = *reinterpret_cast<const float4*>(&W[(k0 + r)*H_SZ + cq + i*4]);
    tile[r][cq + i*4 + 0] = v.x; tile[r][cq + i*4 + 1] = v.y;
    tile[r][cq + i*4 + 2] = v.z; tile[r][cq + i*4 + 3] = v.w;
  }
  __syncthreads();
  int n = tid >> 2, kq = (tid & 3) * 16;
  bf16x8 o0, o1;
  #pragma unroll
  for (int e = 0; e < 8; ++e){
    o0[e] = f2bs(tile[kq + e][n]);
    o1[e] = f2bs(tile[kq + 8 + e][n]);
  }
  *reinterpret_cast<bf16x8*>(&Wt[(mat*64 + n)*C_SZ + k0 + kq])     = o0;
  *reinterpret_cast<bf16x8*>(&Wt[(mat*64 + n)*C_SZ + k0 + kq + 8]) = o1;
}

// --- K1: QKV GEMM, A and B async-staged via global_load_lds, double-buffered ---
__global__ __launch_bounds__(512, 2) void qkv_gemm(const float* __restrict__ x, const short* __restrict__ Wt,
                         short* __restrict__ qb, short* __restrict__ kb, short* __restrict__ vT){
  __shared__ float As[2][2048];             // 16 KB: 32 rows x 64 fp32, chunk16-swizzled
  __shared__ short Bs[2][12288];            // 48 KB: 192 rows x 64 bf16, chunk16-swizzled
  int tid = threadIdx.x;
  int wv = tid >> 6, lane = tid & 63, lhi = lane >> 4, llo = lane & 15;
  int wm = wv >> 2, wn = wv & 3;
  long R0 = (long)blockIdx.x * 32;

  int srow = tid >> 4;
  int schunk = (tid & 15) ^ (srow & 7);
  const float* gsrcA = &x[(R0 + srow)*C_SZ + schunk*4];
  float* ldstA = &As[0][wv*256];

  int bn = tid >> 3;
  int bc = (tid & 7) ^ (bn & 7);
  const short* gsrcB0 = &Wt[(  0 + bn)*C_SZ + bc*8];
  const short* gsrcB1 = &Wt[( 64 + bn)*C_SZ + bc*8];
  const short* gsrcB2 = &Wt[(128 + bn)*C_SZ + bc*8];
  short* ldstB = &Bs[0][wv*512];

  f32x4 acc[3];
  #pragma unroll
  for (int j = 0; j < 3; ++j) acc[j] = (f32x4){0.f,0.f,0.f,0.f};

  int rr = wm*16 + llo;
  int r7 = rr & 7, lhi2 = lhi*2;
  int c0 = ((lhi2    ) ^ r7) << 2;
  int c1 = ((lhi2 + 1) ^ r7) << 2;
  int c2 = ((lhi2 + 8) ^ r7) << 2;
  int c3 = ((lhi2 + 9) ^ r7) << 2;
  int nrow[3];
  #pragma unroll
  for (int j = 0; j < 3; ++j) nrow[j] = (wn*48 + j*16 + llo)*64;
  int llo7 = llo & 7;
  int bo0 = ((    lhi) ^ llo7)*8;
  int bo1 = ((4 + lhi) ^ llo7)*8;

#define STAGE(T, BUF) { \
    gload16(gsrcA  + (T)*64, ldstA + (BUF)*2048); \
    gload16(gsrcB0 + (T)*64, ldstB + (BUF)*12288); \
    gload16(gsrcB1 + (T)*64, ldstB + (BUF)*12288 + 4096); \
    gload16(gsrcB2 + (T)*64, ldstB + (BUF)*12288 + 8192); }

  STAGE(0, 0);
  __syncthreads();

  for (int t = 0; t < 12; ++t){
    int cb = t & 1;
    if (t < 11) STAGE(t + 1, cb ^ 1);
    const float* Ar = &As[cb][rr*64];
    f32x4 a0 = *reinterpret_cast<const f32x4*>(Ar + c0);
    f32x4 a1 = *reinterpret_cast<const f32x4*>(Ar + c1);
    f32x4 a2 = *reinterpret_cast<const f32x4*>(Ar + c2);
    f32x4 a3 = *reinterpret_cast<const f32x4*>(Ar + c3);
    bf16x8 af0, af1;
    #pragma unroll
    for (int e = 0; e < 4; ++e){
      af0[e]   = f2bs(a0[e]); af0[4+e] = f2bs(a1[e]);
      af1[e]   = f2bs(a2[e]); af1[4+e] = f2bs(a3[e]);
    }
    const short* Br = &Bs[cb][0];
    #pragma unroll
    for (int j = 0; j < 3; ++j){
      bf16x8 b0 = *reinterpret_cast<const bf16x8*>(Br + nrow[j] + bo0);
      bf16x8 b1 = *reinterpret_cast<const bf16x8*>(Br + nrow[j] + bo1);
      acc[j] = __builtin_amdgcn_mfma_f32_16x16x32_bf16(af0, b0, acc[j], 0, 0, 0);
      acc[j] = __builtin_amdgcn_mfma_f32_16x16x32_bf16(af1, b1, acc[j], 0, 0, 0);
    }
    __syncthreads();
  }
#undef STAGE

  long mbase = R0 + wm*16 + lhi*4;
  #pragma unroll
  for (int j = 0; j < 3; ++j){
    int n = wn*48 + j*16 + llo;
    int mat = n >> 6, c = n & 63;
    if (mat == 2){
      long b = mbase >> 11, t = mbase & 2047;
      short4v p;
      #pragma unroll
      for (int reg = 0; reg < 4; ++reg) p[reg] = f2bs(acc[j][reg]);
      *reinterpret_cast<short4v*>(&vT[(b*H_SZ + c)*T_SZ + t]) = p;
    } else {
      short* dst = (mat == 0) ? qb : kb;
      #pragma unroll
      for (int reg = 0; reg < 4; ++reg)
        dst[(mbase + reg)*H_SZ + c] = f2bs(acc[j][reg]);
    }
  }
}

// --- K2: flash attention v2 — shared-KV dual q-tile, 8-way kv split, shfl-free softmax ---
__global__ __launch_bounds__(512, 4) void attn_fwd(const short* __restrict__ qb, const short* __restrict__ kb,
                        const short* __restrict__ vT, const float* __restrict__ bsc,
                        float* __restrict__ out){
  __shared__ float bias_s[2048];            // 8 KB
  __shared__ short P_lds[8][2][1152];       // 36.9 KB; aliased as o_part during merge
  __shared__ float m_part[8][16];
  __shared__ float l_part[8][4][16];        // per-lhi l partials (shfl-free l)
  float* OP = (float*)&P_lds[0][0][0];      // merge view: [w][row][d] @ w*1152 + row*65 + d

  int tid = threadIdx.x;
  for (int i = tid; i < 2048; i += 512) bias_s[i] = bsc[i];

  int wv = tid >> 6, lane = tid & 63, lhi = lane >> 4, llo = lane & 15;
  int b = blockIdx.x & 7, jj = blockIdx.x >> 3;   // batch -> XCD affinity
  int qtA = jj, qtB = 127 - jj;             // qtA subset range of qtB
  int qA = qtA*16 + llo, qB = qtB*16 + llo;
  int nktA = (qtA >> 2) + 1, nktB = (qtB >> 2) + 1;

  const short* qrA = &qb[((long)(b*T_SZ + qA))*H_SZ + lhi*8];
  const short* qrB = &qb[((long)(b*T_SZ + qB))*H_SZ + lhi*8];
  bf16x8 qfA0 = *reinterpret_cast<const bf16x8*>(qrA);
  bf16x8 qfA1 = *reinterpret_cast<const bf16x8*>(qrA + 32);
  bf16x8 qfB0 = *reinterpret_cast<const bf16x8*>(qrB);
  bf16x8 qfB1 = *reinterpret_cast<const bf16x8*>(qrB + 32);
  const short* kbase = kb + (long)b*T_SZ*H_SZ;
  const short* vbase = vT + (long)b*H_SZ*T_SZ;
  __syncthreads();

  float mA = -1e30f, lA = 0.f, mB = -1e30f, lB = 0.f;
  f32x4 oA[4], oB[4];
  #pragma unroll
  for (int df = 0; df < 4; ++df){ oA[df] = (f32x4){0.f,0.f,0.f,0.f}; oB[df] = (f32x4){0.f,0.f,0.f,0.f}; }

  // softmax (shfl-free common path) + P write + P-frag read
#define SM(S, M, L, O, QV, TI, PB0, PB1) {                                  \
    _Pragma("unroll") for (int f = 0; f < 4; ++f)                           \
      _Pragma("unroll") for (int rg = 0; rg < 4; ++rg){                     \
        int kv = kv0 + f*16 + lhi*4 + rg;                                   \
        int rel = (QV) - kv;                                                \
        float bv = bias_s[rel > 0 ? rel : 0];                               \
        S[f][rg] = (rel >= 0) ? fmaf(S[f][rg], 0.18033688f, bv) : -1e30f; } \
    f32x4 tm = vmax4(vmax4(S[0], S[1]), vmax4(S[2], S[3]));                 \
    float pmax = fmaxf(fmaxf(tm[0], tm[1]), fmaxf(tm[2], tm[3]));           \
    if (!__all(pmax <= M + 8.0f)){                                          \
      float rm = fmaxf(pmax, __shfl_xor(pmax, 16));                         \
      rm = fmaxf(rm, __shfl_xor(rm, 32));                                   \
      float mnew = fmaxf(M, rm);                                            \
      float corr = exp2f(M - mnew);                                         \
      M = mnew; L *= corr;                                                  \
      _Pragma("unroll") for (int df = 0; df < 4; ++df) O[df] = O[df]*corr; }\
    _Pragma("unroll") for (int f = 0; f < 4; ++f){                          \
      short4v pk;                                                           \
      _Pragma("unroll") for (int rg = 0; rg < 4; ++rg){                     \
        float p = exp2f(S[f][rg] - M); S[f][rg] = p; pk[rg] = f2bs(p); }    \
      *reinterpret_cast<short4v*>(&P_lds[wv][TI][llo*72 + f*16 + lhi*4]) = pk; } \
    f32x4 va = (S[0] + S[1]) + (S[2] + S[3]);                               \
    L += (va[0] + va[1]) + (va[2] + va[3]);                                 \
    PB0 = *reinterpret_cast<const bf16x8*>(&P_lds[wv][TI][llo*72 + lhi*8]); \
    PB1 = *reinterpret_cast<const bf16x8*>(&P_lds[wv][TI][llo*72 + 32 + lhi*8]); }

  for (int c = wv; c < nktB; c += 8){       // each kv-tile loaded ONCE, used by both q-tiles
    int kv0 = c * 64;
    bool doA = c < nktA;
    f32x4 sA[4], sB[4];
    #pragma unroll
    for (int f = 0; f < 4; ++f){
      const short* kr = kbase + (long)(kv0 + f*16 + llo)*H_SZ + lhi*8;
      bf16x8 k0 = *reinterpret_cast<const bf16x8*>(kr);
      bf16x8 k1 = *reinterpret_cast<const bf16x8*>(kr + 32);
      f32x4 t = (f32x4){0.f,0.f,0.f,0.f};
      t = __builtin_amdgcn_mfma_f32_16x16x32_bf16(k0, qfB0, t, 0, 0, 0);
      t = __builtin_amdgcn_mfma_f32_16x16x32_bf16(k1, qfB1, t, 0, 0, 0);
      sB[f] = t;
      f32x4 u = (f32x4){0.f,0.f,0.f,0.f};   // independent second chain (ILP)
      u = __builtin_amdgcn_mfma_f32_16x16x32_bf16(k0, qfA0, u, 0, 0, 0);
      u = __builtin_amdgcn_mfma_f32_16x16x32_bf16(k1, qfA1, u, 0, 0, 0);
      sA[f] = u;
    }
    bf16x8 pbB0, pbB1;
    SM(sB, mB, lB, oB, qB, 1, pbB0, pbB1);
    if (doA){
      bf16x8 pbA0, pbA1;
      SM(sA, mA, lA, oA, qA, 0, pbA0, pbA1);
      #pragma unroll
      for (int df = 0; df < 4; ++df){
        const short* vr = vbase + (long)(df*16 + llo)*T_SZ + kv0 + lhi*8;
        bf16x8 v0 = *reinterpret_cast<const bf16x8*>(vr);
        bf16x8 v1 = *reinterpret_cast<const bf16x8*>(vr + 32);
        oB[df] = __builtin_amdgcn_mfma_f32_16x16x32_bf16(v0, pbB0, oB[df], 0, 0, 0);
        oB[df] = __builtin_amdgcn_mfma_f32_16x16x32_bf16(v1, pbB1, oB[df], 0, 0, 0);
        oA[df] = __builtin_amdgcn_mfma_f32_16x16x32_bf16(v0, pbA0, oA[df], 0, 0, 0);
        oA[df] = __builtin_amdgcn_mfma_f32_16x16x32_bf16(v1, pbA1, oA[df], 0, 0, 0);
      }
    } else {
      #pragma unroll
      for (int df = 0; df < 4; ++df){
        const short* vr = vbase + (long)(df*16 + llo)*T_SZ + kv0 + lhi*8;
        bf16x8 v0 = *reinterpret_cast<const bf16x8*>(vr);
        bf16x8 v1 = *reinterpret_cast<const bf16x8*>(vr + 32);
        oB[df] = __builtin_amdgcn_mfma_f32_16x16x32_bf16(v0, pbB0, oB[df], 0, 0, 0);
        oB[df] = __builtin_amdgcn_mfma_f32_16x16x32_bf16(v1, pbB1, oB[df], 0, 0, 0);
      }
    }
  }
#undef SM

  // two-phase merge (B then A), o_part aliases P_lds region
#define MERGE(O, M, L, QT) {                                                \
    _Pragma("unroll") for (int df = 0; df < 4; ++df)                        \
      _Pragma("unroll") for (int rg = 0; rg < 4; ++rg)                      \
        OP[wv*1152 + llo*65 + df*16 + lhi*4 + rg] = O[df][rg];              \
    l_part[wv][lhi][llo] = L;                                               \
    if (lhi == 0) m_part[wv][llo] = M;                                      \
    __syncthreads();                                                        \
    { int idx = tid;                                                        \
      _Pragma("unroll") for (int rep = 0; rep < 2; ++rep){                  \
        int row = idx >> 6, d = idx & 63;                                   \
        float mstar = m_part[0][row];                                       \
        _Pragma("unroll") for (int w = 1; w < 8; ++w)                       \
          mstar = fmaxf(mstar, m_part[w][row]);                             \
        float lsum = 0.f, osum = 0.f;                                       \
        _Pragma("unroll") for (int w = 0; w < 8; ++w){                      \
          float sc = exp2f(m_part[w][row] - mstar);                         \
          lsum += sc * (l_part[w][0][row] + l_part[w][1][row]               \
                      + l_part[w][2][row] + l_part[w][3][row]);             \
          osum += sc * OP[w*1152 + row*65 + d]; }                           \
        out[((long)(b*T_SZ + (QT)*16 + row))*H_SZ + d] = osum / lsum;       \
        idx += 512; } }                                                     \
    __syncthreads(); }

  MERGE(oB, mB, lB, qtB);
  MERGE(oA, mA, lA, qtA);
#undef MERGE
}

extern "C" void kernel_launch(void* const* d_in, const int* in_sizes, int n_in,
                              void* d_out, int out_size, void* d_ws, size_t ws_size,
                              hipStream_t stream){
  const float* x    = (const float*)d_in[0];
  const float* Wq   = (const float*)d_in[1];
  const float* Wk   = (const float*)d_in[2];
  const float* Wv   = (const float*)d_in[3];
  const float* bias = (const float*)d_in[4];
  float* out = (float*)d_out;

  const size_t NTOK = (size_t)B_SZ * T_SZ * H_SZ;   // 1,048,576
  short* qb = (short*)d_ws;
  short* kb = qb + NTOK;
  short* vT = kb + NTOK;
  short* Wt = vT + NTOK;                            // 192*768 shorts
  float* bsc = (float*)(Wt + 192*C_SZ);             // 2048 floats

  prep_wt<<<44, 256, 0, stream>>>(Wq, Wk, Wv, bias, Wt, bsc);
  qkv_gemm<<<512, 512, 0, stream>>>(x, Wt, qb, kb, vT);
  attn_fwd<<<512, 512, 0, stream>>>(qb, kb, vT, bsc, out);
}